// Round 1
// baseline (531.387 us; speedup 1.0000x reference)
//
#include <hip/hip_runtime.h>
#include <math.h>

// Problem constants (B=8, M=1024, P=256, N=4096)
#define R_ROWS 8192   // B*M rows of X-side
#define NP     4096   // train points
#define DREAL  257    // P+1
#define DPAD   288    // padded to multiple of 32 for BK

#define BM 128
#define BN 128
#define BK 32
#define LDSS 40       // LDS row stride in bf16 units (32 + 8 pad)

using frag8 = __attribute__((ext_vector_type(8))) short;
using f32x4 = __attribute__((ext_vector_type(4))) float;

static __device__ __forceinline__ float bf2f(unsigned short u) {
    return __uint_as_float(((unsigned int)u) << 16);
}
static __device__ __forceinline__ unsigned short f2bf(float f) {
    unsigned int u = __float_as_uint(f);
    unsigned int lsb = (u >> 16) & 1u;
    u += 0x7fffu + lsb;           // round-to-nearest-even
    return (unsigned short)(u >> 16);
}

// ---- prep: build bf16 [row][DPAD] feature matrices + fp32 squared norms ----
__global__ void prep_x(const float* __restrict__ X, const int* __restrict__ A,
                       unsigned short* __restrict__ XAb, float* __restrict__ x2) {
    int row  = blockIdx.x * (blockDim.x >> 6) + (threadIdx.x >> 6);
    int lane = threadIdx.x & 63;
    if (row >= R_ROWS) return;
    const float* xr = X + (size_t)row * 256;
    unsigned short* o = XAb + (size_t)row * DPAD;
    float s = 0.f;
#pragma unroll
    for (int i = 0; i < 4; i++) {
        float v = xr[lane + 64 * i];
        s += v * v;
        o[lane + 64 * i] = f2bf(v);
    }
    if (lane == 0) {
        float a = (float)A[row];
        o[256] = f2bf(a);
        s += a * a;
    }
    if (lane >= 33) o[257 + (lane - 33)] = 0;   // zero pad 257..287
#pragma unroll
    for (int off = 32; off; off >>= 1) s += __shfl_down(s, off, 64);
    if (lane == 0) x2[row] = s;
}

__global__ void prep_z(const float* __restrict__ Z,
                       unsigned short* __restrict__ Zb, float* __restrict__ z2) {
    int row  = blockIdx.x * (blockDim.x >> 6) + (threadIdx.x >> 6);
    int lane = threadIdx.x & 63;
    if (row >= NP) return;
    const float* zr = Z + (size_t)row * DREAL;
    unsigned short* o = Zb + (size_t)row * DPAD;
    float s = 0.f;
#pragma unroll
    for (int i = 0; i < 4; i++) {
        float v = zr[lane + 64 * i];   // 0..255 always < 257
        s += v * v;
        o[lane + 64 * i] = f2bf(v);
    }
    if (lane < 32) {
        int idx = 256 + lane;
        float v = (idx < DREAL) ? zr[idx] : 0.f;
        s += v * v;
        o[idx] = f2bf(v);
    }
#pragma unroll
    for (int off = 32; off; off >>= 1) s += __shfl_down(s, off, 64);
    if (lane == 0) z2[row] = s;
}

// ---- cast K_inv fp32 -> bf16 ----
__global__ void cast_kinv(const float* __restrict__ Ki, unsigned short* __restrict__ Kib) {
    int i = blockIdx.x * blockDim.x + threadIdx.x;   // one float4 per thread
    float4 v = ((const float4*)Ki)[i];
    ushort4 o;
    o.x = f2bf(v.x); o.y = f2bf(v.y); o.z = f2bf(v.z); o.w = f2bf(v.w);
    ((ushort4*)Kib)[i] = o;
}

// ---- GEMM core helper: stage one 128x32 bf16 tile into padded LDS ----
static __device__ __forceinline__ void stage_tile(const unsigned short* __restrict__ g,
                                                  size_t ld, int row0, int kk,
                                                  unsigned short* __restrict__ s, int tid) {
    int r = tid >> 1;                 // 0..127
    int c = (tid & 1) * 16;          // 0 or 16 (bf16 units)
    const unsigned short* gp = g + (size_t)(row0 + r) * ld + kk + c;
    uint4 v0 = *(const uint4*)(gp);
    uint4 v1 = *(const uint4*)(gp + 8);
    *(uint4*)(&s[r * LDSS + c])     = v0;
    *(uint4*)(&s[r * LDSS + c + 8]) = v1;
}

// ---- Kxz = exp(-0.5*max(x2+z2-2*XA@Z^T,0)), stored bf16 ----
__global__ __launch_bounds__(256, 2) void gemm_kxz(
    const unsigned short* __restrict__ Abuf,  // [R_ROWS][DPAD]
    const unsigned short* __restrict__ Bbuf,  // [NP][DPAD]
    const float* __restrict__ x2, const float* __restrict__ z2,
    unsigned short* __restrict__ Kb)          // [R_ROWS][NP]
{
    __shared__ unsigned short sA[BM * LDSS];
    __shared__ unsigned short sB[BN * LDSS];
    const int m0 = blockIdx.x * BM, n0 = blockIdx.y * BN;
    const int tid = threadIdx.x, lane = tid & 63, wave = tid >> 6;
    const int wr = wave >> 1, wc = wave & 1;
    const int q = lane >> 4, rr = lane & 15;

    f32x4 acc[4][4] = {};
    for (int kk = 0; kk < DPAD; kk += BK) {
        stage_tile(Abuf, DPAD, m0, kk, sA, tid);
        stage_tile(Bbuf, DPAD, n0, kk, sB, tid);
        __syncthreads();
        frag8 af[4], bfr[4];
#pragma unroll
        for (int i = 0; i < 4; i++) {
            af[i]  = *(const frag8*)(&sA[(wr * 64 + i * 16 + rr) * LDSS + q * 8]);
            bfr[i] = *(const frag8*)(&sB[(wc * 64 + i * 16 + rr) * LDSS + q * 8]);
        }
#pragma unroll
        for (int i = 0; i < 4; i++)
#pragma unroll
            for (int j = 0; j < 4; j++)
                acc[i][j] = __builtin_amdgcn_mfma_f32_16x16x32_bf16(af[i], bfr[j], acc[i][j], 0, 0, 0);
        __syncthreads();
    }
#pragma unroll
    for (int i = 0; i < 4; i++) {
#pragma unroll
        for (int reg = 0; reg < 4; reg++) {
            int m = m0 + wr * 64 + i * 16 + q * 4 + reg;
            float xm = x2[m];
#pragma unroll
            for (int j = 0; j < 4; j++) {
                int n = n0 + wc * 64 + j * 16 + rr;
                float d = xm + z2[n] - 2.0f * acc[i][j][reg];
                d = fmaxf(d, 0.0f);
                Kb[(size_t)m * NP + n] = f2bf(__expf(-0.5f * d));
            }
        }
    }
}

// ---- f_loc[m] = sum_n Kb[m][n] * alpha[n] ----
__global__ void floc_kernel(const unsigned short* __restrict__ Kb,
                            const float* __restrict__ alpha, float* __restrict__ out) {
    int m    = blockIdx.x * (blockDim.x >> 6) + (threadIdx.x >> 6);
    int lane = threadIdx.x & 63;
    if (m >= R_ROWS) return;
    const unsigned short* kr = Kb + (size_t)m * NP;
    float s = 0.f;
#pragma unroll
    for (int base = 0; base < NP; base += 64 * 8) {
        int idx = base + lane * 8;
        uint4 kv = *(const uint4*)(kr + idx);
        const unsigned short* ks = (const unsigned short*)&kv;
        float4 a0 = *(const float4*)(alpha + idx);
        float4 a1 = *(const float4*)(alpha + idx + 4);
        s += bf2f(ks[0]) * a0.x + bf2f(ks[1]) * a0.y + bf2f(ks[2]) * a0.z + bf2f(ks[3]) * a0.w;
        s += bf2f(ks[4]) * a1.x + bf2f(ks[5]) * a1.y + bf2f(ks[6]) * a1.z + bf2f(ks[7]) * a1.w;
    }
#pragma unroll
    for (int off = 32; off; off >>= 1) s += __shfl_down(s, off, 64);
    if (lane == 0) out[m] = s;
}

// ---- q[m] += sum_t (sum_n Kb[m][n]*Kib[t][n]) * Kb[m][t] ----
__global__ __launch_bounds__(256, 2) void gemm_q(
    const unsigned short* __restrict__ Kb,   // [R_ROWS][NP] bf16
    const unsigned short* __restrict__ Kib,  // [NP][NP] bf16 (row t, col n)
    float* __restrict__ q_acc)
{
    __shared__ unsigned short sA[BM * LDSS];
    __shared__ unsigned short sB[BN * LDSS];
    const int m0 = blockIdx.x * BM, t0 = blockIdx.y * BN;
    const int tid = threadIdx.x, lane = tid & 63, wave = tid >> 6;
    const int wr = wave >> 1, wc = wave & 1;
    const int q = lane >> 4, rr = lane & 15;

    f32x4 acc[4][4] = {};
    for (int kk = 0; kk < NP; kk += BK) {
        stage_tile(Kb,  NP, m0, kk, sA, tid);
        stage_tile(Kib, NP, t0, kk, sB, tid);
        __syncthreads();
        frag8 af[4], bfr[4];
#pragma unroll
        for (int i = 0; i < 4; i++) {
            af[i]  = *(const frag8*)(&sA[(wr * 64 + i * 16 + rr) * LDSS + q * 8]);
            bfr[i] = *(const frag8*)(&sB[(wc * 64 + i * 16 + rr) * LDSS + q * 8]);
        }
#pragma unroll
        for (int i = 0; i < 4; i++)
#pragma unroll
            for (int j = 0; j < 4; j++)
                acc[i][j] = __builtin_amdgcn_mfma_f32_16x16x32_bf16(af[i], bfr[j], acc[i][j], 0, 0, 0);
        __syncthreads();
    }
    // epilogue: multiply by k[m,t], reduce over t (within block strip), atomic into q_acc
#pragma unroll
    for (int i = 0; i < 4; i++) {
#pragma unroll
        for (int reg = 0; reg < 4; reg++) {
            int m = m0 + wr * 64 + i * 16 + q * 4 + reg;
            float s = 0.f;
#pragma unroll
            for (int j = 0; j < 4; j++) {
                int t = t0 + wc * 64 + j * 16 + rr;
                s += acc[i][j][reg] * bf2f(Kb[(size_t)m * NP + t]);
            }
            s += __shfl_xor(s, 1, 64);
            s += __shfl_xor(s, 2, 64);
            s += __shfl_xor(s, 4, 64);
            s += __shfl_xor(s, 8, 64);
            if (rr == 0) atomicAdd(&q_acc[m], s);
        }
    }
}

__global__ void finalize(const float* __restrict__ q_acc, float* __restrict__ out) {
    int m = blockIdx.x * blockDim.x + threadIdx.x;
    if (m < R_ROWS) out[R_ROWS + m] = 1.0f - q_acc[m];
}

extern "C" void kernel_launch(void* const* d_in, const int* in_sizes, int n_in,
                              void* d_out, int out_size, void* d_ws, size_t ws_size,
                              hipStream_t stream) {
    const float* X     = (const float*)d_in[0];
    const int*   A     = (const int*)d_in[1];
    const float* Z     = (const float*)d_in[2];   // XA_train [4096][257]
    const float* alpha = (const float*)d_in[3];
    const float* Kinv  = (const float*)d_in[4];
    float* out = (float*)d_out;

    // workspace carve (all 256B aligned); total ~103 MB
    char* ws = (char*)d_ws;
    unsigned short* XAb = (unsigned short*)(ws);                 //  4,718,592 B
    unsigned short* Zb  = (unsigned short*)(ws + 4718592);       //  2,359,296 B
    float* x2    = (float*)(ws + 7077888);                       //     32,768 B
    float* z2    = (float*)(ws + 7110656);                       //     16,384 B
    float* q_acc = (float*)(ws + 7127040);                       //     32,768 B
    unsigned short* Kib = (unsigned short*)(ws + 7159808);       // 33,554,432 B
    unsigned short* Kb  = (unsigned short*)(ws + 40714240);      // 67,108,864 B

    hipMemsetAsync(q_acc, 0, R_ROWS * sizeof(float), stream);
    prep_x<<<R_ROWS / 4, 256, 0, stream>>>(X, A, XAb, x2);
    prep_z<<<NP / 4, 256, 0, stream>>>(Z, Zb, z2);
    cast_kinv<<<(NP * NP / 4) / 256, 256, 0, stream>>>(Kinv, Kib);
    gemm_kxz<<<dim3(R_ROWS / BM, NP / BN), 256, 0, stream>>>(XAb, Zb, x2, z2, Kb);
    floc_kernel<<<R_ROWS / 4, 256, 0, stream>>>(Kb, alpha, out);
    gemm_q<<<dim3(R_ROWS / BM, NP / BN), 256, 0, stream>>>(Kb, Kib, q_acc);
    finalize<<<R_ROWS / 256, 256, 0, stream>>>(q_acc, out);
}

// Round 2
// 153.301 us; speedup vs baseline: 3.4663x; 3.4663x over previous
//
#include <hip/hip_runtime.h>
#include <math.h>

// Problem constants (B=8, M=1024, P=256, N=4096)
#define R_ROWS 8192   // B*M rows of X-side
#define NP     4096   // train points
#define DREAL  257    // P+1
#define DPAD   288    // padded to multiple of 32 for BK

#define BM 128
#define BN 128
#define BK 32
#define LDSS 40       // LDS row stride in bf16 units (32 + 8 pad)

using frag8 = __attribute__((ext_vector_type(8))) short;
using f32x4 = __attribute__((ext_vector_type(4))) float;

static __device__ __forceinline__ float bf2f(unsigned short u) {
    return __uint_as_float(((unsigned int)u) << 16);
}
static __device__ __forceinline__ unsigned short f2bf(float f) {
    unsigned int u = __float_as_uint(f);
    unsigned int lsb = (u >> 16) & 1u;
    u += 0x7fffu + lsb;           // round-to-nearest-even
    return (unsigned short)(u >> 16);
}

// ---- prep: build bf16 [row][DPAD] feature matrices + fp32 squared norms ----
__global__ void prep_x(const float* __restrict__ X, const int* __restrict__ A,
                       unsigned short* __restrict__ XAb, float* __restrict__ x2) {
    int row  = blockIdx.x * (blockDim.x >> 6) + (threadIdx.x >> 6);
    int lane = threadIdx.x & 63;
    if (row >= R_ROWS) return;
    const float* xr = X + (size_t)row * 256;
    unsigned short* o = XAb + (size_t)row * DPAD;
    float s = 0.f;
#pragma unroll
    for (int i = 0; i < 4; i++) {
        float v = xr[lane + 64 * i];
        s += v * v;
        o[lane + 64 * i] = f2bf(v);
    }
    if (lane == 0) {
        float a = (float)A[row];
        o[256] = f2bf(a);
        s += a * a;
    }
    if (lane >= 33) o[257 + (lane - 33)] = 0;   // zero pad 257..287
#pragma unroll
    for (int off = 32; off; off >>= 1) s += __shfl_down(s, off, 64);
    if (lane == 0) x2[row] = s;
}

__global__ void prep_z(const float* __restrict__ Z,
                       unsigned short* __restrict__ Zb, float* __restrict__ z2) {
    int row  = blockIdx.x * (blockDim.x >> 6) + (threadIdx.x >> 6);
    int lane = threadIdx.x & 63;
    if (row >= NP) return;
    const float* zr = Z + (size_t)row * DREAL;
    unsigned short* o = Zb + (size_t)row * DPAD;
    float s = 0.f;
#pragma unroll
    for (int i = 0; i < 4; i++) {
        float v = zr[lane + 64 * i];   // 0..255 always < 257
        s += v * v;
        o[lane + 64 * i] = f2bf(v);
    }
    if (lane < 32) {
        int idx = 256 + lane;
        float v = (idx < DREAL) ? zr[idx] : 0.f;
        s += v * v;
        o[idx] = f2bf(v);
    }
#pragma unroll
    for (int off = 32; off; off >>= 1) s += __shfl_down(s, off, 64);
    if (lane == 0) z2[row] = s;
}

// ---- cast K_inv fp32 -> bf16 (gated: skipped when Kb is entirely zero) ----
__global__ void cast_kinv(const float* __restrict__ Ki, unsigned short* __restrict__ Kib,
                          const int* __restrict__ anyflag) {
    if (*anyflag == 0) return;
    int i = blockIdx.x * blockDim.x + threadIdx.x;   // one float4 per thread
    float4 v = ((const float4*)Ki)[i];
    ushort4 o;
    o.x = f2bf(v.x); o.y = f2bf(v.y); o.z = f2bf(v.z); o.w = f2bf(v.w);
    ((ushort4*)Kib)[i] = o;
}

// ---- GEMM core helper: stage one 128x32 bf16 tile into padded LDS ----
static __device__ __forceinline__ void stage_tile(const unsigned short* __restrict__ g,
                                                  size_t ld, int row0, int kk,
                                                  unsigned short* __restrict__ s, int tid) {
    int r = tid >> 1;                 // 0..127
    int c = (tid & 1) * 16;          // 0 or 16 (bf16 units)
    const unsigned short* gp = g + (size_t)(row0 + r) * ld + kk + c;
    uint4 v0 = *(const uint4*)(gp);
    uint4 v1 = *(const uint4*)(gp + 8);
    *(uint4*)(&s[r * LDSS + c])     = v0;
    *(uint4*)(&s[r * LDSS + c + 8]) = v1;
}

// ---- Kxz = exp(-0.5*max(x2+z2-2*XA@Z^T,0)), stored bf16; sets sparsity flags ----
__global__ __launch_bounds__(256, 2) void gemm_kxz(
    const unsigned short* __restrict__ Abuf,  // [R_ROWS][DPAD]
    const unsigned short* __restrict__ Bbuf,  // [NP][DPAD]
    const float* __restrict__ x2, const float* __restrict__ z2,
    unsigned short* __restrict__ Kb,          // [R_ROWS][NP]
    int* __restrict__ rowflag, int* __restrict__ anyflag)
{
    __shared__ unsigned short sA[BM * LDSS];
    __shared__ unsigned short sB[BN * LDSS];
    const int m0 = blockIdx.x * BM, n0 = blockIdx.y * BN;
    const int tid = threadIdx.x, lane = tid & 63, wave = tid >> 6;
    const int wr = wave >> 1, wc = wave & 1;
    const int q = lane >> 4, rr = lane & 15;

    f32x4 acc[4][4] = {};
    for (int kk = 0; kk < DPAD; kk += BK) {
        stage_tile(Abuf, DPAD, m0, kk, sA, tid);
        stage_tile(Bbuf, DPAD, n0, kk, sB, tid);
        __syncthreads();
        frag8 af[4], bfr[4];
#pragma unroll
        for (int i = 0; i < 4; i++) {
            af[i]  = *(const frag8*)(&sA[(wr * 64 + i * 16 + rr) * LDSS + q * 8]);
            bfr[i] = *(const frag8*)(&sB[(wc * 64 + i * 16 + rr) * LDSS + q * 8]);
        }
#pragma unroll
        for (int i = 0; i < 4; i++)
#pragma unroll
            for (int j = 0; j < 4; j++)
                acc[i][j] = __builtin_amdgcn_mfma_f32_16x16x32_bf16(af[i], bfr[j], acc[i][j], 0, 0, 0);
        __syncthreads();
    }
    unsigned int any = 0;
#pragma unroll
    for (int i = 0; i < 4; i++) {
#pragma unroll
        for (int reg = 0; reg < 4; reg++) {
            int m = m0 + wr * 64 + i * 16 + q * 4 + reg;
            float xm = x2[m];
#pragma unroll
            for (int j = 0; j < 4; j++) {
                int n = n0 + wc * 64 + j * 16 + rr;
                float d = xm + z2[n] - 2.0f * acc[i][j][reg];
                d = fmaxf(d, 0.0f);
                unsigned short bv = f2bf(__expf(-0.5f * d));
                any |= bv;
                Kb[(size_t)m * NP + n] = bv;
            }
        }
    }
    // one atomic per wave, only when this wave produced a nonzero bf16 value
    unsigned long long b = __ballot(any != 0);
    if (lane == 0 && b != 0ULL) {
        atomicOr(&rowflag[m0 >> 7], 1);
        atomicOr(anyflag, 1);
    }
}

// ---- f_loc[m] = sum_n Kb[m][n] * alpha[n]; skips all-zero row blocks ----
__global__ void floc_kernel(const unsigned short* __restrict__ Kb,
                            const float* __restrict__ alpha, float* __restrict__ out,
                            const int* __restrict__ rowflag) {
    int m    = blockIdx.x * (blockDim.x >> 6) + (threadIdx.x >> 6);
    int lane = threadIdx.x & 63;
    if (m >= R_ROWS) return;
    if (rowflag[m >> 7] == 0) {                // bit-identical to dotting a zero row
        if (lane == 0) out[m] = 0.0f;
        return;
    }
    const unsigned short* kr = Kb + (size_t)m * NP;
    float s = 0.f;
#pragma unroll
    for (int base = 0; base < NP; base += 64 * 8) {
        int idx = base + lane * 8;
        uint4 kv = *(const uint4*)(kr + idx);
        const unsigned short* ks = (const unsigned short*)&kv;
        float4 a0 = *(const float4*)(alpha + idx);
        float4 a1 = *(const float4*)(alpha + idx + 4);
        s += bf2f(ks[0]) * a0.x + bf2f(ks[1]) * a0.y + bf2f(ks[2]) * a0.z + bf2f(ks[3]) * a0.w;
        s += bf2f(ks[4]) * a1.x + bf2f(ks[5]) * a1.y + bf2f(ks[6]) * a1.z + bf2f(ks[7]) * a1.w;
    }
#pragma unroll
    for (int off = 32; off; off >>= 1) s += __shfl_down(s, off, 64);
    if (lane == 0) out[m] = s;
}

// ---- q[m] += sum_t (sum_n Kb[m][n]*Kib[t][n]) * Kb[m][t]; skips zero row blocks ----
__global__ __launch_bounds__(256, 2) void gemm_q(
    const unsigned short* __restrict__ Kb,   // [R_ROWS][NP] bf16
    const unsigned short* __restrict__ Kib,  // [NP][NP] bf16 (row t, col n)
    float* __restrict__ q_acc,
    const int* __restrict__ rowflag)
{
    const int m0 = blockIdx.x * BM, t0 = blockIdx.y * BN;
    if (rowflag[m0 >> 7] == 0) return;       // A-tile all zero -> contribution is exactly 0

    __shared__ unsigned short sA[BM * LDSS];
    __shared__ unsigned short sB[BN * LDSS];
    const int tid = threadIdx.x, lane = tid & 63, wave = tid >> 6;
    const int wr = wave >> 1, wc = wave & 1;
    const int q = lane >> 4, rr = lane & 15;

    f32x4 acc[4][4] = {};
    for (int kk = 0; kk < NP; kk += BK) {
        stage_tile(Kb,  NP, m0, kk, sA, tid);
        stage_tile(Kib, NP, t0, kk, sB, tid);
        __syncthreads();
        frag8 af[4], bfr[4];
#pragma unroll
        for (int i = 0; i < 4; i++) {
            af[i]  = *(const frag8*)(&sA[(wr * 64 + i * 16 + rr) * LDSS + q * 8]);
            bfr[i] = *(const frag8*)(&sB[(wc * 64 + i * 16 + rr) * LDSS + q * 8]);
        }
#pragma unroll
        for (int i = 0; i < 4; i++)
#pragma unroll
            for (int j = 0; j < 4; j++)
                acc[i][j] = __builtin_amdgcn_mfma_f32_16x16x32_bf16(af[i], bfr[j], acc[i][j], 0, 0, 0);
        __syncthreads();
    }
#pragma unroll
    for (int i = 0; i < 4; i++) {
#pragma unroll
        for (int reg = 0; reg < 4; reg++) {
            int m = m0 + wr * 64 + i * 16 + q * 4 + reg;
            float s = 0.f;
#pragma unroll
            for (int j = 0; j < 4; j++) {
                int t = t0 + wc * 64 + j * 16 + rr;
                s += acc[i][j][reg] * bf2f(Kb[(size_t)m * NP + t]);
            }
            s += __shfl_xor(s, 1, 64);
            s += __shfl_xor(s, 2, 64);
            s += __shfl_xor(s, 4, 64);
            s += __shfl_xor(s, 8, 64);
            if (rr == 0) atomicAdd(&q_acc[m], s);
        }
    }
}

__global__ void finalize(const float* __restrict__ q_acc, float* __restrict__ out) {
    int m = blockIdx.x * blockDim.x + threadIdx.x;
    if (m < R_ROWS) out[R_ROWS + m] = 1.0f - q_acc[m];
}

extern "C" void kernel_launch(void* const* d_in, const int* in_sizes, int n_in,
                              void* d_out, int out_size, void* d_ws, size_t ws_size,
                              hipStream_t stream) {
    const float* X     = (const float*)d_in[0];
    const int*   A     = (const int*)d_in[1];
    const float* Z     = (const float*)d_in[2];   // XA_train [4096][257]
    const float* alpha = (const float*)d_in[3];
    const float* Kinv  = (const float*)d_in[4];
    float* out = (float*)d_out;

    // workspace carve (256B aligned); total ~108 MB
    char* ws = (char*)d_ws;
    unsigned short* XAb = (unsigned short*)(ws);                 //  4,718,592 B
    unsigned short* Zb  = (unsigned short*)(ws + 4718592);       //  2,359,296 B
    float* x2      = (float*)(ws + 7077888);                     //     32,768 B
    float* z2      = (float*)(ws + 7110656);                     //     16,384 B
    float* q_acc   = (float*)(ws + 7127040);                     //     32,768 B
    int*   rowflag = (int*)  (ws + 7159808);                     //        256 B (64 used)
    int*   anyflag = (int*)  (ws + 7160064);                     //        256 B (4 used)
    unsigned short* Kib = (unsigned short*)(ws + 7160320);       // 33,554,432 B
    unsigned short* Kb  = (unsigned short*)(ws + 40714752);      // 67,108,864 B

    // zero q_acc + rowflag + anyflag in one memset
    hipMemsetAsync(q_acc, 0, 32768 + 512, stream);
    prep_x<<<R_ROWS / 4, 256, 0, stream>>>(X, A, XAb, x2);
    prep_z<<<NP / 4, 256, 0, stream>>>(Z, Zb, z2);
    gemm_kxz<<<dim3(R_ROWS / BM, NP / BN), 256, 0, stream>>>(XAb, Zb, x2, z2, Kb, rowflag, anyflag);
    cast_kinv<<<(NP * NP / 4) / 256, 256, 0, stream>>>(Kinv, Kib, anyflag);
    floc_kernel<<<R_ROWS / 4, 256, 0, stream>>>(Kb, alpha, out, rowflag);
    gemm_q<<<dim3(R_ROWS / BM, NP / BN), 256, 0, stream>>>(Kb, Kib, q_acc, rowflag);
    finalize<<<R_ROWS / 256, 256, 0, stream>>>(q_acc, out);
}

// Round 3
// 147.382 us; speedup vs baseline: 3.6055x; 1.0402x over previous
//
#include <hip/hip_runtime.h>
#include <math.h>

// Problem constants (B=8, M=1024, P=256, N=4096)
#define R_ROWS 8192   // B*M rows of X-side
#define NP     4096   // train points
#define DREAL  257    // P+1
#define DPAD   288    // padded to multiple of 32 for BK

#define BM 128
#define BN 128
#define BK 32
#define LDSS 40       // LDS row stride in bf16 units (32 + 8 pad)
#define TSTR 136      // epilogue tile stride in ushorts (128 + 8; 272 B = 16B-aligned rows)

using frag8 = __attribute__((ext_vector_type(8))) short;
using f32x4 = __attribute__((ext_vector_type(4))) float;

static __device__ __forceinline__ float bf2f(unsigned short u) {
    return __uint_as_float(((unsigned int)u) << 16);
}
static __device__ __forceinline__ unsigned short f2bf(float f) {
    unsigned int u = __float_as_uint(f);
    unsigned int lsb = (u >> 16) & 1u;
    u += 0x7fffu + lsb;           // round-to-nearest-even
    return (unsigned short)(u >> 16);
}

// ---- prep: build bf16 [row][DPAD] feature matrices + fp32 squared norms ----
// rows [0, R_ROWS) -> X side;  rows [R_ROWS, R_ROWS+NP) -> train side
__global__ void prep_all(const float* __restrict__ X, const int* __restrict__ A,
                         const float* __restrict__ Z,
                         unsigned short* __restrict__ XAb, unsigned short* __restrict__ Zb,
                         float* __restrict__ x2, float* __restrict__ z2) {
    int row  = blockIdx.x * (blockDim.x >> 6) + (threadIdx.x >> 6);
    int lane = threadIdx.x & 63;
    float s = 0.f;
    if (row < R_ROWS) {
        const float* xr = X + (size_t)row * 256;
        unsigned short* o = XAb + (size_t)row * DPAD;
#pragma unroll
        for (int i = 0; i < 4; i++) {
            float v = xr[lane + 64 * i];
            s += v * v;
            o[lane + 64 * i] = f2bf(v);
        }
        if (lane == 0) {
            float a = (float)A[row];
            o[256] = f2bf(a);
            s += a * a;
        }
        if (lane >= 33) o[257 + (lane - 33)] = 0;   // zero pad 257..287
#pragma unroll
        for (int off = 32; off; off >>= 1) s += __shfl_down(s, off, 64);
        if (lane == 0) x2[row] = s;
    } else {
        int zr_i = row - R_ROWS;
        if (zr_i >= NP) return;
        const float* zr = Z + (size_t)zr_i * DREAL;
        unsigned short* o = Zb + (size_t)zr_i * DPAD;
#pragma unroll
        for (int i = 0; i < 4; i++) {
            float v = zr[lane + 64 * i];
            s += v * v;
            o[lane + 64 * i] = f2bf(v);
        }
        if (lane < 32) {
            int idx = 256 + lane;
            float v = (idx < DREAL) ? zr[idx] : 0.f;
            s += v * v;
            o[idx] = f2bf(v);
        }
#pragma unroll
        for (int off = 32; off; off >>= 1) s += __shfl_down(s, off, 64);
        if (lane == 0) z2[zr_i] = s;
    }
}

// ---- stage one 128x32 bf16 tile into padded LDS ----
static __device__ __forceinline__ void stage_tile(const unsigned short* __restrict__ g,
                                                  size_t ld, int row0, int kk,
                                                  unsigned short* __restrict__ s, int tid) {
    int r = tid >> 1;                // 0..127
    int c = (tid & 1) * 16;         // 0 or 16 (bf16 units)
    const unsigned short* gp = g + (size_t)(row0 + r) * ld + kk + c;
    uint4 v0 = *(const uint4*)(gp);
    uint4 v1 = *(const uint4*)(gp + 8);
    *(uint4*)(&s[r * LDSS + c])     = v0;
    *(uint4*)(&s[r * LDSS + c + 8]) = v1;
}

// ---- stage one 128x32 tile from fp32 source, casting to bf16 ----
static __device__ __forceinline__ void stage_tile_f32(const float* __restrict__ g,
                                                      size_t ld, int row0, int kk,
                                                      unsigned short* __restrict__ s, int tid) {
    int r = tid >> 1;
    int c = (tid & 1) * 16;
    const float* gp = g + (size_t)(row0 + r) * ld + kk + c;
    unsigned short tmp[16];
#pragma unroll
    for (int i = 0; i < 4; i++) {
        float4 v = *(const float4*)(gp + i * 4);
        tmp[i * 4 + 0] = f2bf(v.x); tmp[i * 4 + 1] = f2bf(v.y);
        tmp[i * 4 + 2] = f2bf(v.z); tmp[i * 4 + 3] = f2bf(v.w);
    }
    *(uint4*)(&s[r * LDSS + c])     = *(const uint4*)(tmp);
    *(uint4*)(&s[r * LDSS + c + 8]) = *(const uint4*)(tmp + 8);
}

// ---- Kxz tile kernel: GEMM + exp epilogue + fused f_loc + gated tile write ----
__global__ __launch_bounds__(256, 4) void gemm_kxz(
    const unsigned short* __restrict__ Abuf,  // [R_ROWS][DPAD]
    const unsigned short* __restrict__ Bbuf,  // [NP][DPAD]
    const float* __restrict__ x2, const float* __restrict__ z2,
    const float* __restrict__ alpha,
    unsigned short* __restrict__ Kb,          // [R_ROWS][NP]  (tiles written only if nonzero)
    float* __restrict__ floc_out,             // [R_ROWS] pre-zeroed; atomic accum
    int* __restrict__ rowflag, int* __restrict__ tileflag)
{
    __shared__ union {
        struct { unsigned short a[BM * LDSS]; unsigned short b[BN * LDSS]; } ab;
        unsigned short tile[BM * TSTR];
    } sh;
    __shared__ int sAny;
    const int m0 = blockIdx.x * BM, n0 = blockIdx.y * BN;
    const int tid = threadIdx.x, lane = tid & 63, wave = tid >> 6;
    const int wr = wave >> 1, wc = wave & 1;
    const int q = lane >> 4, rr = lane & 15;
    if (tid == 0) sAny = 0;          // first __syncthreads below makes this visible

    f32x4 acc[4][4] = {};
    for (int kk = 0; kk < DPAD; kk += BK) {
        stage_tile(Abuf, DPAD, m0, kk, sh.ab.a, tid);
        stage_tile(Bbuf, DPAD, n0, kk, sh.ab.b, tid);
        __syncthreads();
        frag8 af[4], bfr[4];
#pragma unroll
        for (int i = 0; i < 4; i++) {
            af[i]  = *(const frag8*)(&sh.ab.a[(wr * 64 + i * 16 + rr) * LDSS + q * 8]);
            bfr[i] = *(const frag8*)(&sh.ab.b[(wc * 64 + i * 16 + rr) * LDSS + q * 8]);
        }
#pragma unroll
        for (int i = 0; i < 4; i++)
#pragma unroll
            for (int j = 0; j < 4; j++)
                acc[i][j] = __builtin_amdgcn_mfma_f32_16x16x32_bf16(af[i], bfr[j], acc[i][j], 0, 0, 0);
        __syncthreads();
    }
    // epilogue: values -> LDS tile (overwrites dead sA/sB); fused f_loc partial dots
    float zn[4], av[4];
#pragma unroll
    for (int j = 0; j < 4; j++) {
        int n = n0 + wc * 64 + j * 16 + rr;
        zn[j] = z2[n];
        av[j] = alpha[n];
    }
    unsigned int any = 0;
#pragma unroll
    for (int i = 0; i < 4; i++) {
#pragma unroll
        for (int reg = 0; reg < 4; reg++) {
            int ml = wr * 64 + i * 16 + q * 4 + reg;
            float xm = x2[m0 + ml];
            float s = 0.f;
#pragma unroll
            for (int j = 0; j < 4; j++) {
                float d = fmaxf(xm + zn[j] - 2.0f * acc[i][j][reg], 0.0f);
                unsigned short bv = f2bf(__expf(-0.5f * d));
                any |= bv;
                sh.tile[ml * TSTR + wc * 64 + j * 16 + rr] = bv;
                s += bf2f(bv) * av[j];
            }
            s += __shfl_xor(s, 1, 64);
            s += __shfl_xor(s, 2, 64);
            s += __shfl_xor(s, 4, 64);
            s += __shfl_xor(s, 8, 64);
            if (rr == 0 && s != 0.0f) atomicAdd(&floc_out[m0 + ml], s);
        }
    }
    if (any) atomicOr(&sAny, 1);
    __syncthreads();
    if (sAny) {
        // coalesced copy-out: 2 threads/row, 4x uint4 each
        int r = tid >> 1, h = (tid & 1) * 64;
        unsigned short* dst = Kb + (size_t)(m0 + r) * NP + n0 + h;
        const unsigned short* src = &sh.tile[r * TSTR + h];
#pragma unroll
        for (int k = 0; k < 4; k++)
            *(uint4*)(dst + k * 16) = *(const uint4*)(src + k * 16);
        if (tid == 0) {
            tileflag[blockIdx.x * 32 + blockIdx.y] = 1;
            atomicOr(&rowflag[blockIdx.x], 1);
        }
    }
}

// ---- q[m] += sum_t (sum_n Kb[m][n]*Kinv_bf[t][n]) * Kb[m][t]; tile-gated ----
__global__ __launch_bounds__(256, 4) void gemm_q(
    const unsigned short* __restrict__ Kb,   // [R_ROWS][NP] bf16 (sparse-tiled)
    const float* __restrict__ Kinv,          // [NP][NP] fp32, cast during staging
    float* __restrict__ q_acc,
    const int* __restrict__ rowflag, const int* __restrict__ tileflag)
{
    const int m0 = blockIdx.x * BM, t0 = blockIdx.y * BN;
    if (rowflag[blockIdx.x] == 0) return;    // entire A row-block zero -> exact 0

    __shared__ unsigned short sA[BM * LDSS];
    __shared__ unsigned short sB[BN * LDSS];
    const int tid = threadIdx.x, lane = tid & 63, wave = tid >> 6;
    const int wr = wave >> 1, wc = wave & 1;
    const int q = lane >> 4, rr = lane & 15;
    const int mblk = blockIdx.x * 32;

    f32x4 acc[4][4] = {};
    for (int kb = 0; kb < 32; kb++) {
        if (tileflag[mblk + kb] == 0) continue;   // A-tile all zero: contribution exact 0
        int kk = kb * 128;
#pragma unroll
        for (int k2 = 0; k2 < 128; k2 += BK) {
            stage_tile(Kb, NP, m0, kk + k2, sA, tid);
            stage_tile_f32(Kinv, NP, t0, kk + k2, sB, tid);
            __syncthreads();
            frag8 af[4], bfr[4];
#pragma unroll
            for (int i = 0; i < 4; i++) {
                af[i]  = *(const frag8*)(&sA[(wr * 64 + i * 16 + rr) * LDSS + q * 8]);
                bfr[i] = *(const frag8*)(&sB[(wc * 64 + i * 16 + rr) * LDSS + q * 8]);
            }
#pragma unroll
            for (int i = 0; i < 4; i++)
#pragma unroll
                for (int j = 0; j < 4; j++)
                    acc[i][j] = __builtin_amdgcn_mfma_f32_16x16x32_bf16(af[i], bfr[j], acc[i][j], 0, 0, 0);
            __syncthreads();
        }
    }
    if (tileflag[mblk + (t0 >> 7)] == 0) return;  // Kb[m][t] block zero -> s == 0 exactly
#pragma unroll
    for (int i = 0; i < 4; i++) {
#pragma unroll
        for (int reg = 0; reg < 4; reg++) {
            int m = m0 + wr * 64 + i * 16 + q * 4 + reg;
            float s = 0.f;
#pragma unroll
            for (int j = 0; j < 4; j++) {
                int t = t0 + wc * 64 + j * 16 + rr;
                s += acc[i][j][reg] * bf2f(Kb[(size_t)m * NP + t]);
            }
            s += __shfl_xor(s, 1, 64);
            s += __shfl_xor(s, 2, 64);
            s += __shfl_xor(s, 4, 64);
            s += __shfl_xor(s, 8, 64);
            if (rr == 0 && s != 0.0f) atomicAdd(&q_acc[m], s);
        }
    }
}

__global__ void finalize(const float* __restrict__ q_acc, float* __restrict__ out) {
    int m = blockIdx.x * blockDim.x + threadIdx.x;
    if (m < R_ROWS) out[R_ROWS + m] = 1.0f - q_acc[m];
}

extern "C" void kernel_launch(void* const* d_in, const int* in_sizes, int n_in,
                              void* d_out, int out_size, void* d_ws, size_t ws_size,
                              hipStream_t stream) {
    const float* X     = (const float*)d_in[0];
    const int*   A     = (const int*)d_in[1];
    const float* Z     = (const float*)d_in[2];   // XA_train [4096][257]
    const float* alpha = (const float*)d_in[3];
    const float* Kinv  = (const float*)d_in[4];
    float* out = (float*)d_out;

    // workspace carve (256B aligned); total ~74 MB
    char* ws = (char*)d_ws;
    unsigned short* XAb = (unsigned short*)(ws);                 //  4,718,592 B
    unsigned short* Zb  = (unsigned short*)(ws + 4718592);       //  2,359,296 B
    float* x2       = (float*)(ws + 7077888);                    //     32,768 B
    float* z2       = (float*)(ws + 7110656);                    //     16,384 B
    float* q_acc    = (float*)(ws + 7127040);                    //     32,768 B
    int*   rowflag  = (int*)  (ws + 7159808);                    //        256 B (64 used)
    int*   tileflag = (int*)  (ws + 7160064);                    //      8,192 B (64x32)
    unsigned short* Kb = (unsigned short*)(ws + 7168256);        // 67,108,864 B

    // zero q_acc + rowflag + tileflag (contiguous) and the f_loc accumulation region
    hipMemsetAsync(q_acc, 0, 32768 + 256 + 8192, stream);
    hipMemsetAsync(out, 0, R_ROWS * sizeof(float), stream);
    prep_all<<<(R_ROWS + NP) / 4, 256, 0, stream>>>(X, A, Z, XAb, Zb, x2, z2);
    gemm_kxz<<<dim3(R_ROWS / BM, NP / BN), 256, 0, stream>>>(XAb, Zb, x2, z2, alpha, Kb,
                                                             out, rowflag, tileflag);
    gemm_q<<<dim3(R_ROWS / BM, NP / BN), 256, 0, stream>>>(Kb, Kinv, q_acc, rowflag, tileflag);
    finalize<<<R_ROWS / 256, 256, 0, stream>>>(q_acc, out);
}